// Round 9
// baseline (2374.820 us; speedup 1.0000x reference)
//
#include <hip/hip_runtime.h>
#include <hip/hip_cooperative_groups.h>
#include <math.h>

namespace cg = cooperative_groups;

// SegmentalLM forward. V=4000 E=H=256 M=128 B=32 L=4, S=126, NROW=5*4032=20160.
//
// R9: ONE cooperative mega-kernel (256 blocks x 512 thr x 152KB LDS, 1 block/CU)
// with grid.sync() phase barriers, replacing 13 dispatches. R8 accounting showed
// ~430us of dispatch-coupled overhead (small MFMA dispatches cost ~40-50us each
// regardless of work; fusion deltas confirm overhead scales with dispatch count).
// Phase bodies are R8's verified kernels. Encoder: explicit in-loop L2 weight
// streaming (23/32 slots; 9 in LDS) - the accepted ~2.2us/step floor (R7 showed
// the allocator spills any attempt at VGPR residency).

#define LOGNEG -1000000.0f
#define GF_BIAS 1
#define GF_TANH 2
#define GF_F16OUT 16
#define ZSHIFT 8.0f

typedef unsigned int uint32;
typedef _Float16 half2_t __attribute__((ext_vector_type(2)));
typedef _Float16 half8_t __attribute__((ext_vector_type(8)));
typedef float    f32x4_t __attribute__((ext_vector_type(4)));

__device__ __forceinline__ float sigmf_(float x){ return 1.0f/(1.0f+expf(-x)); }

__device__ __forceinline__ float dot2f(uint32 w, uint32 h, float acc){
#if __has_builtin(__builtin_amdgcn_fdot2)
    return __builtin_amdgcn_fdot2(__builtin_bit_cast(half2_t, w),
                                  __builtin_bit_cast(half2_t, h), acc, false);
#else
    half2_t a = __builtin_bit_cast(half2_t, w);
    half2_t b = __builtin_bit_cast(half2_t, h);
    return acc + (float)a[0]*(float)b[0] + (float)a[1]*(float)b[1];
#endif
}

struct MegaArgs {
    const int *x, *lengths;
    const float *emb, *e2v_b, *eWih, *eWhh, *ebih, *ebhh, *h0, *c0;
    const float *dWih, *dWhh, *dbih, *dbhh, *dhtW, *dht_b, *sosW, *sos_b;
    float* out;
    _Float16 *emb16, *eWih16, *dWih16, *dWhh16, *eWhh16, *sosW16, *dhtW16;
    _Float16 *emb_in16, *XgE16, *Xgdec16, *gb16, *enc_out16, *sos16, *dech0_16, *dec16;
    float *biasOff, *bias_e, *bias_d, *is_s, *dec_c, *ps, *pzt, *pze, *tlp, *eosb, *seg_g;
};

// ---- 64x64 f16 MFMA tile: stage B (256 thr engine) ----
__device__ __forceinline__ void tile_stage_B(
    _Float16* Bs, int ltid, const _Float16* __restrict__ W, int colBlk)
{
    #pragma unroll
    for (int i = 0; i < 8; i++){
        int idx = i*256 + ltid;
        int row = idx >> 5, c16 = idx & 31;
        *(uint4*)&Bs[row*264 + c16*8] =
            *(const uint4*)(W + (size_t)(colBlk+row)*256 + c16*8);
    }
}

// ---- 64x64 f16 MFMA tile: compute + epilogue (256 thr engine) ----
__device__ __forceinline__ void tile_mfma_store(
    const _Float16* Bs, int ltid, const _Float16* __restrict__ A,
    const float* __restrict__ bias, float* __restrict__ C,
    _Float16* __restrict__ C16, int N, int flags, int rowBlk, int colBlk)
{
    int wave = ltid >> 6, lane = ltid & 63;
    int ln = lane & 15, quad = lane >> 4;
    half8_t a[8];
    const half8_t* Ap = (const half8_t*)(A + (size_t)(rowBlk + wave*16 + ln)*256 + quad*8);
    #pragma unroll
    for (int ks = 0; ks < 8; ks++) a[ks] = Ap[ks*4];
    #pragma unroll
    for (int ct = 0; ct < 4; ct++){
        f32x4_t c4 = {0.f,0.f,0.f,0.f};
        const _Float16* bp = &Bs[(ct*16+ln)*264 + quad*8];
        #pragma unroll
        for (int ks = 0; ks < 8; ks++){
            half8_t b = *(const half8_t*)(bp + ks*32);
            c4 = __builtin_amdgcn_mfma_f32_16x16x32_f16(a[ks], b, c4, 0, 0, 0);
        }
        int c = colBlk + ct*16 + ln;
        #pragma unroll
        for (int reg = 0; reg < 4; reg++){
            int r = rowBlk + wave*16 + quad*4 + reg;
            float v = c4[reg];
            if (flags & GF_BIAS) v += bias[c];
            if (flags & GF_TANH) v = tanhf(v);
            if (flags & GF_F16OUT) C16[(size_t)r*N + c] = (_Float16)v;
            else                   C  [(size_t)r*N + c] = v;
        }
    }
}

__global__ void __launch_bounds__(512, 2) k_mega(MegaArgs A)
{
    extern __shared__ char smem[];
    cg::grid_group grid = cg::this_grid();
    const int bid = blockIdx.x;       // 0..255
    const int tid = threadIdx.x;      // 0..511
    const size_t gid = (size_t)bid*512 + tid;
    const size_t GS = 131072;

    // ================= P0: packs / gathers / biases =================
    for (size_t i = gid; i < (size_t)4032*256; i += GS){
        int row = (int)(i >> 8);
        A.emb16[i] = (row < 4000) ? (_Float16)A.emb[i] : (_Float16)0.0f;
    }
    for (size_t i = gid; i < 4032; i += GS)
        A.biasOff[i] = (i < 4000) ? (A.e2v_b[i] - ZSHIFT) : -200.0f;
    for (size_t i = gid; i < (size_t)4*262144; i += GS){
        int w = (int)(i >> 18); size_t e = i & 262143;
        const float* src = (w==0)?A.eWih:(w==1)?A.dWih:(w==2)?A.dWhh:A.eWhh;
        _Float16* dst = (w==0)?A.eWih16:(w==1)?A.dWih16:(w==2)?A.dWhh16:A.eWhh16;
        dst[e] = (_Float16)src[e];
    }
    for (size_t i = gid; i < (size_t)2*65536; i += GS){
        int w = (int)(i >> 16); size_t e = i & 65535;
        const float* src = w ? A.dhtW : A.sosW;
        _Float16* dst = w ? A.dhtW16 : A.sosW16;
        dst[e] = (_Float16)src[e];
    }
    for (size_t i = gid; i < (size_t)4096*256; i += GS){
        int ri = (int)(i >> 8), c = (int)(i & 255);
        int m = ri >> 5, b = ri & 31;
        int tok = A.x[b*128 + m];
        A.emb_in16[i] = (_Float16)A.emb[(size_t)tok*256 + c];
    }
    for (size_t i = gid; i < 4096; i += GS){
        int m = (int)(i >> 5), b = (int)(i & 31);
        int tok = A.x[b*128 + m];
        A.is_s[i] = (tok <= 2) ? LOGNEG : 0.0f;
    }
    for (size_t i = gid; i < 1024; i += GS){
        A.bias_e[i] = A.ebih[i] + A.ebhh[i];
        A.bias_d[i] = A.dbih[i] + A.dbhh[i];
    }
    grid.sync();   // 1

    // ================= P1: XgE = emb_in16 @ eWih^T + bias_e (1024 tiles, dual engine) =================
    {
        int eng = tid >> 8, ltid = tid & 255;
        _Float16* Bs = (_Float16*)smem + (size_t)eng*(64*264);
        for (int rnd = 0; rnd < 2; rnd++){
            int tile = rnd*512 + bid*2 + eng;
            __syncthreads();
            if (tile < 1024) tile_stage_B(Bs, ltid, A.eWih16, (tile & 15)*64);
            __syncthreads();
            if (tile < 1024) tile_mfma_store(Bs, ltid, A.emb_in16, A.bias_e, nullptr,
                A.XgE16, 1024, GF_BIAS|GF_F16OUT, (tile >> 4)*64, (tile & 15)*64);
        }
    }
    grid.sync();   // 2

    // ================= P2: encoder (blocks 0..31) || Xgdec GEMM (blocks 32..255) =================
    if (bid < 32){
        uint4*  wlds = (uint4*)smem;                   // [9][1024]
        uint32* h_u  = (uint32*)(smem + 147456);       // 128 dwords
        float*  g_s  = (float*)(smem + 147968);        // 1024
        const int b = bid;
        const int r0 = tid, r1 = tid + 512;
        const uint4* p0 = (const uint4*)(A.eWhh16 + (size_t)r0*256);
        const uint4* p1 = (const uint4*)(A.eWhh16 + (size_t)r1*256);
        #pragma unroll
        for (int i = 0; i < 9; i++){
            wlds[i*1024 + r0] = p0[23 + i];
            wlds[i*1024 + r1] = p1[23 + i];
        }
        float c = 0.f;
        if (tid < 256){
            c = A.c0[tid];
            ((_Float16*)h_u)[tid] = (_Float16)A.h0[tid];
        }
        __syncthreads();
        const uint4* hu4 = (const uint4*)h_u;
        float xg0 = (float)A.XgE16[(size_t)b*1024 + r0];
        float xg1 = (float)A.XgE16[(size_t)b*1024 + r1];
        for (int t = 0; t < 128; t++){
            float nxg0 = 0.f, nxg1 = 0.f;
            if (t < 127){
                nxg0 = (float)A.XgE16[((size_t)((t+1)*32+b))*1024 + r0];
                nxg1 = (float)A.XgE16[((size_t)((t+1)*32+b))*1024 + r1];
            }
            float a0 = 0.f, a1 = 0.f;
            #pragma unroll
            for (int i = 0; i < 23; i++){
                uint4 w0v = p0[i], w1v = p1[i];
                uint4 hh = hu4[i];
                a0 = dot2f(w0v.x, hh.x, a0); a0 = dot2f(w0v.y, hh.y, a0);
                a0 = dot2f(w0v.z, hh.z, a0); a0 = dot2f(w0v.w, hh.w, a0);
                a1 = dot2f(w1v.x, hh.x, a1); a1 = dot2f(w1v.y, hh.y, a1);
                a1 = dot2f(w1v.z, hh.z, a1); a1 = dot2f(w1v.w, hh.w, a1);
            }
            #pragma unroll
            for (int i = 0; i < 9; i++){
                uint4 hh = hu4[23 + i];
                uint4 v0 = wlds[i*1024 + r0];
                uint4 v1 = wlds[i*1024 + r1];
                a0 = dot2f(v0.x, hh.x, a0); a0 = dot2f(v0.y, hh.y, a0);
                a0 = dot2f(v0.z, hh.z, a0); a0 = dot2f(v0.w, hh.w, a0);
                a1 = dot2f(v1.x, hh.x, a1); a1 = dot2f(v1.y, hh.y, a1);
                a1 = dot2f(v1.z, hh.z, a1); a1 = dot2f(v1.w, hh.w, a1);
            }
            g_s[r0] = a0 + xg0;
            g_s[r1] = a1 + xg1;
            __syncthreads();
            if (tid < 256){
                float gi = g_s[tid], gf = g_s[256+tid], gg = g_s[512+tid], go = g_s[768+tid];
                c = sigmf_(gf)*c + sigmf_(gi)*tanhf(gg);
                float hn = sigmf_(go)*tanhf(c);
                A.enc_out16[((size_t)(t*32+b))*256 + tid] = (_Float16)(0.5f*hn);
                ((_Float16*)h_u)[tid] = (_Float16)hn;
            }
            __syncthreads();
            xg0 = nxg0; xg1 = nxg1;
        }
    } else {
        int eng = tid >> 8, ltid = tid & 255;
        _Float16* Bs = (_Float16*)smem + (size_t)eng*(64*264);
        int base = (bid - 32)*2 + eng;      // 0..447
        for (int rnd = 0; rnd < 3; rnd++){
            int tile = rnd*448 + base;
            __syncthreads();
            if (tile < 1024) tile_stage_B(Bs, ltid, A.dWih16, (tile & 15)*64);
            __syncthreads();
            if (tile < 1024) tile_mfma_store(Bs, ltid, A.emb_in16, A.bias_d, nullptr,
                A.Xgdec16, 1024, GF_BIAS|GF_F16OUT, (tile >> 4)*64, (tile & 15)*64);
        }
    }
    grid.sync();   // 3

    // ================= P3a: heads (sos: tiles 0..251, dech0: 252..503) =================
    {
        int eng = tid >> 8, ltid = tid & 255;
        _Float16* Bs = (_Float16*)smem + (size_t)eng*(64*264);
        int tile = bid*2 + eng;             // 0..511
        int z = (tile >= 252);
        int t2 = z ? tile - 252 : tile;
        __syncthreads();
        if (tile < 504) tile_stage_B(Bs, ltid, z ? A.dhtW16 : A.sosW16, (t2 & 3)*64);
        __syncthreads();
        if (tile < 504) tile_mfma_store(Bs, ltid, A.enc_out16,
            z ? A.dht_b : A.sos_b, nullptr, z ? A.dech0_16 : A.sos16, 256,
            z ? (GF_BIAS|GF_TANH|GF_F16OUT) : (GF_BIAS|GF_F16OUT),
            (t2 >> 2)*64, (t2 & 3)*64);
    }
    grid.sync();   // 4

    // ================= P3b: gb = sos16 @ dWih^T + bias_d (1008 tiles) =================
    {
        int eng = tid >> 8, ltid = tid & 255;
        _Float16* Bs = (_Float16*)smem + (size_t)eng*(64*264);
        for (int rnd = 0; rnd < 2; rnd++){
            int tile = rnd*512 + bid*2 + eng;
            __syncthreads();
            if (tile < 1008) tile_stage_B(Bs, ltid, A.dWih16, (tile & 15)*64);
            __syncthreads();
            if (tile < 1008) tile_mfma_store(Bs, ltid, A.sos16, A.bias_d, nullptr,
                A.gb16, 1024, GF_BIAS|GF_F16OUT, (tile >> 4)*64, (tile & 15)*64);
        }
    }
    grid.sync();   // 5

    // ================= P4: 5 fused decoder steps (252 virtual tiles each) =================
    for (int j = 0; j < 5; j++){
        if (bid < 252){
            _Float16* Bs = (_Float16*)smem;
            int u0 = (bid & 3)*64, r0 = (bid >> 2)*64;
            const _Float16* hprev = (j == 0) ? A.dech0_16 : (A.dec16 + (size_t)(j-1)*4032*256);
            const _Float16* base16 = (j == 0) ? A.gb16 : A.Xgdec16;
            _Float16* dec_j = A.dec16 + (size_t)j*4032*256;

            int wave = tid >> 6, lane = tid & 63;
            int ln = lane & 15, quad = lane >> 4;
            half8_t a[8];
            if (tid < 256){
                const half8_t* Ap = (const half8_t*)(hprev + (size_t)(r0 + wave*16 + ln)*256 + quad*8);
                #pragma unroll
                for (int ks = 0; ks < 8; ks++) a[ks] = Ap[ks*4];
            }
            f32x4_t cg4[4][4];
            #pragma unroll
            for (int g = 0; g < 4; g++){
                __syncthreads();
                #pragma unroll
                for (int i = 0; i < 4; i++){       // 512-thread stage
                    int idx = i*512 + tid;
                    int row = idx >> 5, c16 = idx & 31;
                    *(uint4*)&Bs[row*264 + c16*8] =
                        *(const uint4*)(A.dWhh16 + (size_t)(g*256 + u0 + row)*256 + c16*8);
                }
                __syncthreads();
                if (tid < 256){
                    #pragma unroll
                    for (int ct = 0; ct < 4; ct++){
                        f32x4_t c4 = {0.f,0.f,0.f,0.f};
                        const _Float16* bp = &Bs[(ct*16+ln)*264 + quad*8];
                        #pragma unroll
                        for (int ks = 0; ks < 8; ks++){
                            half8_t b = *(const half8_t*)(bp + ks*32);
                            c4 = __builtin_amdgcn_mfma_f32_16x16x32_f16(a[ks], b, c4, 0, 0, 0);
                        }
                        cg4[g][ct] = c4;
                    }
                }
            }
            if (tid < 256){
                #pragma unroll
                for (int ct = 0; ct < 4; ct++){
                    int u = u0 + ct*16 + ln;
                    #pragma unroll
                    for (int reg = 0; reg < 4; reg++){
                        int r = r0 + wave*16 + quad*4 + reg;
                        float bi, bf, bg, bo;
                        if (j == 0){
                            const _Float16* bp = base16 + (size_t)r*1024 + u;
                            bi = (float)bp[0]; bf = (float)bp[256]; bg = (float)bp[512]; bo = (float)bp[768];
                        } else {
                            int s = r >> 5, b_ = r & 31;
                            int m = s + j;
                            if (m < 128){
                                const _Float16* bp = base16 + (size_t)(m*32+b_)*1024 + u;
                                bi = (float)bp[0]; bf = (float)bp[256]; bg = (float)bp[512]; bo = (float)bp[768];
                            } else {
                                bi = A.bias_d[u]; bf = A.bias_d[256+u]; bg = A.bias_d[512+u]; bo = A.bias_d[768+u];
                            }
                        }
                        float gi = cg4[0][ct][reg] + bi;
                        float gf = cg4[1][ct][reg] + bf;
                        float gg = cg4[2][ct][reg] + bg;
                        float go = cg4[3][ct][reg] + bo;
                        float cv = (j == 0) ? 0.0f : A.dec_c[(size_t)r*256 + u];
                        cv = sigmf_(gf)*cv + sigmf_(gi)*tanhf(gg);
                        float hv = sigmf_(go)*tanhf(cv);
                        A.dec_c[(size_t)r*256 + u] = cv;
                        dec_j[(size_t)r*256 + u] = (_Float16)hv;
                    }
                }
            }
        }
        grid.sync();   // 6..10
    }

    // ================= P5: logits (1260 virtual tiles: 315 row-blocks x 4 quarters) =================
    {
        _Float16* Bs = (_Float16*)smem;
        int* tgt_s = (int*)(smem + 64*264*2);
        for (int rnd = 0; rnd < 5; rnd++){
            int v = rnd*256 + bid;
            if (v < 1260){
                int r0 = (v % 315)*64;
                int q  = v / 315;
                int vt0 = q*16, vt1 = (q == 3) ? 63 : (vt0 + 16);
                int wave = tid >> 6, lane = tid & 63;
                int ln = lane & 15, quad = lane >> 4;

                __syncthreads();
                if (tid < 64){
                    int r = r0 + tid;
                    int t = r / 4032, sb = r % 4032;
                    int s_ = sb >> 5, b = sb & 31;
                    int m = s_ + 1 + t;
                    tgt_s[tid] = (m < 128) ? A.x[b*128 + m] : 0;
                }
                half8_t a[8];
                if (tid < 256){
                    const half8_t* Ap = (const half8_t*)(A.dec16 + (size_t)(r0 + wave*16 + ln)*256 + quad*8);
                    #pragma unroll
                    for (int ks = 0; ks < 8; ks++) a[ks] = Ap[ks*4];
                }
                __syncthreads();
                int tg[4];
                if (tid < 256){
                    #pragma unroll
                    for (int reg = 0; reg < 4; reg++) tg[reg] = tgt_s[wave*16 + quad*4 + reg];
                }
                float s[4]   = {0.f,0.f,0.f,0.f};
                float rzt[4] = {-1e30f,-1e30f,-1e30f,-1e30f};
                float rze[4] = {-1e30f,-1e30f,-1e30f,-1e30f};

                for (int vt = vt0; vt < vt1; vt++){
                    int v0 = vt*64;
                    __syncthreads();
                    #pragma unroll
                    for (int i = 0; i < 4; i++){   // 512-thread stage
                        int idx = i*512 + tid;
                        int row = idx >> 5, c16 = idx & 31;
                        *(uint4*)&Bs[row*264 + c16*8] =
                            *(const uint4*)(A.emb16 + (size_t)(v0+row)*256 + c16*8);
                    }
                    __syncthreads();
                    if (tid < 256){
                        #pragma unroll
                        for (int ct = 0; ct < 4; ct++){
                            f32x4_t c4 = {0.f,0.f,0.f,0.f};
                            const _Float16* bp = &Bs[(ct*16+ln)*264 + quad*8];
                            #pragma unroll
                            for (int ks = 0; ks < 8; ks++){
                                half8_t b = *(const half8_t*)(bp + ks*32);
                                c4 = __builtin_amdgcn_mfma_f32_16x16x32_f16(a[ks], b, c4, 0, 0, 0);
                            }
                            int vv = v0 + ct*16 + ln;
                            float bb = A.biasOff[vv];
                            #pragma unroll
                            for (int reg = 0; reg < 4; reg++){
                                float z = c4[reg] + bb;
                                s[reg] += __expf(z);
                                if (vv == tg[reg]) rzt[reg] = z;
                                if (vv == 3)       rze[reg] = z;
                            }
                        }
                    }
                }
                if (tid < 256){
                    #pragma unroll
                    for (int reg = 0; reg < 4; reg++){
                        float vsum = s[reg], vzt = rzt[reg], vze = rze[reg];
                        #pragma unroll
                        for (int off = 1; off < 16; off <<= 1){
                            vsum += __shfl_xor(vsum, off, 64);
                            vzt = fmaxf(vzt, __shfl_xor(vzt, off, 64));
                            vze = fmaxf(vze, __shfl_xor(vze, off, 64));
                        }
                        if (ln == 0){
                            int r = r0 + wave*16 + quad*4 + reg;
                            A.ps [q*20160 + r] = vsum;
                            A.pzt[q*20160 + r] = vzt;
                            A.pze[q*20160 + r] = vze;
                        }
                    }
                }
            }
        }
    }
    grid.sync();   // 11

    // ================= P6: combine quarters -> tlp / eosb =================
    if (gid < 20160){
        int r = (int)gid;
        float lse = __logf(A.ps[r] + A.ps[20160+r] + A.ps[2*20160+r] + A.ps[3*20160+r]);
        int t = r / 4032, sb = r % 4032;
        int s_ = sb >> 5, b = sb & 31;
        int m = s_ + 1 + t;
        int tg = (m < 128) ? A.x[b*128 + m] : 0;
        float zt = A.pzt[(tg >> 10)*20160 + r];   // quarters 1024-col aligned
        float ze = A.pze[r];                       // EOS=3 -> quarter 0
        if (t < 4)  A.tlp[(t*126+s_)*32 + b]      = zt - lse;
        if (t >= 1) A.eosb[((t-1)*126+s_)*32 + b] = ze - lse;
    }
    grid.sync();   // 12

    // ================= P7: segmental DP + reduction (block 0) =================
    if (bid == 0){
        float* tlpL = (float*)smem;          // 16128
        float* eosL = tlpL + 16128;          // 16128
        float* isL  = eosL + 16128;          // 4096
        for (int i = tid; i < 16128; i += 512){ tlpL[i] = A.tlp[i]; eosL[i] = A.eosb[i]; }
        for (int i = tid; i < 4096;  i += 512){ isL[i] = A.is_s[i]; }
        __syncthreads();
        if (tid < 128){
            int k = tid >> 5, b = tid & 31;
            for (int s = 0; s < 126; s++){
                float cum = 0.f;
                for (int kk = 0; kk <= k; kk++) cum += tlpL[(kk*126+s)*32 + b];
                if (k >= 1){
                    for (int kk = 1; kk <= k; kk++){
                        int m = s+1+kk;
                        if (m < 128) cum += isL[m*32+b];
                    }
                    cum += isL[(s+1)*32 + b];
                }
                float lp = cum + eosL[(k*126+s)*32 + b];
                int jl = min(4, 126 - s);
                if (k >= jl) lp = LOGNEG;
                A.seg_g[(s*4+k)*32 + b] = lp;
            }
        }
        __syncthreads();
        __shared__ float nll_s[32];
        if (tid < 32){
            int target = A.lengths[tid] - 2;
            float b0 = 0.f, b1 = LOGNEG, b2 = LOGNEG, b3 = LOGNEG;
            float nllb = 0.f;
            for (int e = 1; e <= 126; e++){
                float v0 = b0 + A.seg_g[((e-1)*4+0)*32 + tid];
                float v1 = b1 + ((e >= 2) ? A.seg_g[((e-2)*4+1)*32 + tid] : LOGNEG);
                float v2 = b2 + ((e >= 3) ? A.seg_g[((e-3)*4+2)*32 + tid] : LOGNEG);
                float v3 = b3 + ((e >= 4) ? A.seg_g[((e-4)*4+3)*32 + tid] : LOGNEG);
                float mx = fmaxf(fmaxf(v0,v1), fmaxf(v2,v3));
                float a = mx + logf(expf(v0-mx)+expf(v1-mx)+expf(v2-mx)+expf(v3-mx));
                if (e == target) nllb = -a;
                b3 = b2; b2 = b1; b1 = b0; b0 = a;
            }
            nll_s[tid] = nllb;
        }
        __syncthreads();
        if (tid == 0){
            float tot = 0.f; int lsum = 0;
            for (int i = 0; i < 32; i++){ tot += nll_s[i]; lsum += A.lengths[i]; }
            A.out[0] = tot / (float)(lsum - 64);
        }
    }
}

extern "C" void kernel_launch(void* const* d_in, const int* in_sizes, int n_in,
                              void* d_out, int out_size, void* d_ws, size_t ws_size,
                              hipStream_t stream)
{
    MegaArgs M;
    M.x       = (const int*)  d_in[0];
    M.lengths = (const int*)  d_in[1];
    M.emb     = (const float*)d_in[2];
    M.e2v_b   = (const float*)d_in[3];
    M.eWih    = (const float*)d_in[4];
    M.eWhh    = (const float*)d_in[5];
    M.ebih    = (const float*)d_in[6];
    M.ebhh    = (const float*)d_in[7];
    M.h0      = (const float*)d_in[8];
    M.c0      = (const float*)d_in[9];
    M.dWih    = (const float*)d_in[10];
    M.dWhh    = (const float*)d_in[11];
    M.dbih    = (const float*)d_in[12];
    M.dbhh    = (const float*)d_in[13];
    M.dhtW    = (const float*)d_in[14];
    M.dht_b   = (const float*)d_in[15];
    M.sosW    = (const float*)d_in[16];
    M.sos_b   = (const float*)d_in[17];
    M.out     = (float*)d_out;

    char* wsb = (char*)d_ws;
    size_t off = 0;
    auto alloc = [&](size_t bytes)->void*{
        void* p = (void*)(wsb + off);
        off += ((bytes + 255)/256)*256;
        return p;
    };
    M.emb16    = (_Float16*)alloc((size_t)4032*256*2);
    M.eWih16   = (_Float16*)alloc((size_t)1024*256*2);
    M.dWih16   = (_Float16*)alloc((size_t)1024*256*2);
    M.dWhh16   = (_Float16*)alloc((size_t)1024*256*2);
    M.eWhh16   = (_Float16*)alloc((size_t)1024*256*2);
    M.sosW16   = (_Float16*)alloc((size_t)256*256*2);
    M.dhtW16   = (_Float16*)alloc((size_t)256*256*2);
    M.emb_in16 = (_Float16*)alloc((size_t)4096*256*2);
    M.XgE16    = (_Float16*)alloc((size_t)4096*1024*2);
    M.Xgdec16  = (_Float16*)alloc((size_t)4096*1024*2);
    M.gb16     = (_Float16*)alloc((size_t)4032*1024*2);
    M.enc_out16= (_Float16*)alloc((size_t)4096*256*2);
    M.sos16    = (_Float16*)alloc((size_t)4032*256*2);
    M.dech0_16 = (_Float16*)alloc((size_t)4032*256*2);
    M.dec16    = (_Float16*)alloc((size_t)5*4032*256*2);
    M.biasOff  = (float*)alloc(4032*4);
    M.bias_e   = (float*)alloc(1024*4);
    M.bias_d   = (float*)alloc(1024*4);
    M.is_s     = (float*)alloc(4096*4);
    M.dec_c    = (float*)alloc((size_t)4032*256*4);
    M.ps       = (float*)alloc((size_t)4*20160*4);
    M.pzt      = (float*)alloc((size_t)4*20160*4);
    M.pze      = (float*)alloc((size_t)4*20160*4);
    M.tlp      = (float*)alloc((size_t)4*126*32*4);
    M.eosb     = (float*)alloc((size_t)4*126*32*4);
    M.seg_g    = (float*)alloc((size_t)126*4*32*4);
    (void)ws_size; (void)in_sizes; (void)n_in; (void)out_size;

    hipFuncSetAttribute(reinterpret_cast<const void*>(k_mega),
                        hipFuncAttributeMaxDynamicSharedMemorySize, 152064);

    void* kargs[] = { (void*)&M };
    hipLaunchCooperativeKernel(reinterpret_cast<const void*>(k_mega),
                               dim3(256), dim3(512), kargs, 152064, stream);
}

// Round 10
// 1032.192 us; speedup vs baseline: 2.3008x; 2.3008x over previous
//
#include <hip/hip_runtime.h>
#include <math.h>

// SegmentalLM forward. V=4000 E=H=256 M=128 B=32 L=4, S=126, NROW=5*4032=20160.
//
// R9 FAILED: cooperative mega-kernel — grid.sync() ~125us each on 8 non-coherent
// XCD L2s (dirty-L2 flush per sync) -> 2375us. Lesson: fuse only block-locally.
// R10: R8 structure, 13 -> 6 dispatches:
//   k_prep   = packs + gather + XgE GEMM from raw f32 (no deps)
//   k_enc    = recurrence (32 blk) + Xgdec GEMM on idle CUs (R8 verbatim, 286us)
//   k_decoder= heads + ALL 5 decoder steps in-block (h in LDS, c in VGPRs,
//              gb never materialized) — replaces 7 dispatches
//   k_logits = 315x4 quarters + inline tgt/EOS (R8 verbatim)
//   k_comb_fin = combine + last-finisher finalize (atomic, agent scope)

#define LOGNEG -1000000.0f
#define GF_BIAS 1
#define GF_F16OUT 16
#define ZSHIFT 8.0f

typedef unsigned int uint32;
typedef _Float16 half2_t __attribute__((ext_vector_type(2)));
typedef _Float16 half8_t __attribute__((ext_vector_type(8)));
typedef float    f32x4_t __attribute__((ext_vector_type(4)));

__device__ __forceinline__ float sigmf_(float x){ return 1.0f/(1.0f+expf(-x)); }

__device__ __forceinline__ float dot2f(uint32 w, uint32 h, float acc){
#if __has_builtin(__builtin_amdgcn_fdot2)
    return __builtin_amdgcn_fdot2(__builtin_bit_cast(half2_t, w),
                                  __builtin_bit_cast(half2_t, h), acc, false);
#else
    half2_t a = __builtin_bit_cast(half2_t, w);
    half2_t b = __builtin_bit_cast(half2_t, h);
    return acc + (float)a[0]*(float)b[0] + (float)a[1]*(float)b[1];
#endif
}

// ---- 64x64 f16 MFMA tile body (256-thr engine; threads >=256 idle) ----
__device__ __forceinline__ void gemm16_body(
    _Float16* Bs, int tid,
    const _Float16* __restrict__ A, const _Float16* __restrict__ W,
    const float* __restrict__ bias, float* __restrict__ C,
    _Float16* __restrict__ C16, int N, int flags, int rowBlk, int colBlk)
{
    int wave = tid >> 6, lane = tid & 63;
    int ln = lane & 15, quad = lane >> 4;
    half8_t a[8];
    if (tid < 256){
        #pragma unroll
        for (int i = 0; i < 8; i++){
            int idx = i*256 + tid;
            int row = idx >> 5, c16 = idx & 31;
            *(uint4*)&Bs[row*264 + c16*8] =
                *(const uint4*)(W + (size_t)(colBlk+row)*256 + c16*8);
        }
        const half8_t* Ap = (const half8_t*)(A + (size_t)(rowBlk + wave*16 + ln)*256 + quad*8);
        #pragma unroll
        for (int ks = 0; ks < 8; ks++) a[ks] = Ap[ks*4];
    }
    __syncthreads();
    if (tid < 256){
        #pragma unroll
        for (int ct = 0; ct < 4; ct++){
            f32x4_t c4 = {0.f,0.f,0.f,0.f};
            const _Float16* bp = &Bs[(ct*16+ln)*264 + quad*8];
            #pragma unroll
            for (int ks = 0; ks < 8; ks++){
                half8_t b = *(const half8_t*)(bp + ks*32);
                c4 = __builtin_amdgcn_mfma_f32_16x16x32_f16(a[ks], b, c4, 0, 0, 0);
            }
            int c = colBlk + ct*16 + ln;
            #pragma unroll
            for (int reg = 0; reg < 4; reg++){
                int r = rowBlk + wave*16 + quad*4 + reg;
                float v = c4[reg];
                if (flags & GF_BIAS) v += bias[c];
                if (flags & GF_F16OUT) C16[(size_t)r*N + c] = (_Float16)v;
                else                   C  [(size_t)r*N + c] = v;
            }
        }
    }
}

// ---------------- k_prep: packs + gather + XgE GEMM from raw f32 ----------------
// 0..4031 emb16+biasOff | 4032..5055 dWih16 | 5056..6079 dWhh16 | 6080..7103 eWhh16
// 7104..7359 sosW16 | 7360..7615 dhtW16 | 7616..7619 bias_d | 7620..11715 gather
// 11716..12739 XgE tiles (raw f32 A via token gather, raw f32 B convert)
__global__ __launch_bounds__(256) void k_prep(
    const int* __restrict__ x,
    const float* __restrict__ emb, const float* __restrict__ e2v_b,
    const float* __restrict__ eWih, const float* __restrict__ dWih,
    const float* __restrict__ dWhh, const float* __restrict__ eWhh,
    const float* __restrict__ sosW, const float* __restrict__ dhtW,
    const float* __restrict__ ebih, const float* __restrict__ ebhh,
    const float* __restrict__ dbih, const float* __restrict__ dbhh,
    _Float16* __restrict__ emb16, float* __restrict__ biasOff,
    _Float16* __restrict__ dWih16, _Float16* __restrict__ dWhh16,
    _Float16* __restrict__ eWhh16, _Float16* __restrict__ sosW16,
    _Float16* __restrict__ dhtW16, float* __restrict__ bias_d,
    _Float16* __restrict__ emb_in16, float* __restrict__ is_s,
    _Float16* __restrict__ XgE16)
{
    __shared__ _Float16 Bs[64*264];
    int bx = blockIdx.x, tid = threadIdx.x;
    if (bx < 4032){
        int row = bx;
        emb16[(size_t)row*256 + tid] = (row < 4000) ? (_Float16)emb[(size_t)row*256 + tid] : (_Float16)0.0f;
        if (tid == 0) biasOff[row] = (row < 4000) ? (e2v_b[row] - ZSHIFT) : -200.0f;
    } else if (bx < 5056){
        int r = bx - 4032; dWih16[(size_t)r*256 + tid] = (_Float16)dWih[(size_t)r*256 + tid];
    } else if (bx < 6080){
        int r = bx - 5056; dWhh16[(size_t)r*256 + tid] = (_Float16)dWhh[(size_t)r*256 + tid];
    } else if (bx < 7104){
        int r = bx - 6080; eWhh16[(size_t)r*256 + tid] = (_Float16)eWhh[(size_t)r*256 + tid];
    } else if (bx < 7360){
        int r = bx - 7104; sosW16[(size_t)r*256 + tid] = (_Float16)sosW[(size_t)r*256 + tid];
    } else if (bx < 7616){
        int r = bx - 7360; dhtW16[(size_t)r*256 + tid] = (_Float16)dhtW[(size_t)r*256 + tid];
    } else if (bx < 7620){
        int j = (bx - 7616)*256 + tid;
        if (j < 1024) bias_d[j] = dbih[j] + dbhh[j];
    } else if (bx < 11716){
        int ri = bx - 7620;               // < 4096
        int m = ri >> 5, b = ri & 31;
        int tok = x[b*128 + m];
        emb_in16[(size_t)ri*256 + tid] = (_Float16)emb[(size_t)tok*256 + tid];
        if (tid == 0) is_s[ri] = (tok <= 2) ? LOGNEG : 0.0f;
    } else {
        // XgE tile from raw f32: XgE = emb[x] @ eWih^T + (ebih+ebhh)
        int tile = bx - 11716;            // < 1024
        int rowBlk = (tile >> 4)*64, colBlk = (tile & 15)*64;
        #pragma unroll
        for (int i = 0; i < 8; i++){
            int idx = i*256 + tid;
            int row = idx >> 5, c16 = idx & 31;
            const float* src = eWih + (size_t)(colBlk+row)*256 + c16*8;
            float4 f0 = *(const float4*)src;
            float4 f1 = *(const float4*)(src + 4);
            half8_t hv;
            hv[0]=(_Float16)f0.x; hv[1]=(_Float16)f0.y; hv[2]=(_Float16)f0.z; hv[3]=(_Float16)f0.w;
            hv[4]=(_Float16)f1.x; hv[5]=(_Float16)f1.y; hv[6]=(_Float16)f1.z; hv[7]=(_Float16)f1.w;
            *(half8_t*)&Bs[row*264 + c16*8] = hv;
        }
        int wave = tid >> 6, lane = tid & 63;
        int ln = lane & 15, quad = lane >> 4;
        int r = rowBlk + wave*16 + ln;
        int m = r >> 5, b_ = r & 31;
        int tok = x[b_*128 + m];
        half8_t a[8];
        #pragma unroll
        for (int ks = 0; ks < 8; ks++){
            const float* ap = emb + (size_t)tok*256 + quad*8 + ks*32;
            float4 f0 = *(const float4*)ap;
            float4 f1 = *(const float4*)(ap + 4);
            half8_t hv;
            hv[0]=(_Float16)f0.x; hv[1]=(_Float16)f0.y; hv[2]=(_Float16)f0.z; hv[3]=(_Float16)f0.w;
            hv[4]=(_Float16)f1.x; hv[5]=(_Float16)f1.y; hv[6]=(_Float16)f1.z; hv[7]=(_Float16)f1.w;
            a[ks] = hv;
        }
        __syncthreads();
        #pragma unroll
        for (int ct = 0; ct < 4; ct++){
            f32x4_t c4 = {0.f,0.f,0.f,0.f};
            const _Float16* bp = &Bs[(ct*16+ln)*264 + quad*8];
            #pragma unroll
            for (int ks = 0; ks < 8; ks++){
                half8_t b = *(const half8_t*)(bp + ks*32);
                c4 = __builtin_amdgcn_mfma_f32_16x16x32_f16(a[ks], b, c4, 0, 0, 0);
            }
            int c = colBlk + ct*16 + ln;
            float bb = ebih[c] + ebhh[c];
            #pragma unroll
            for (int reg = 0; reg < 4; reg++){
                int rr = rowBlk + wave*16 + quad*4 + reg;
                XgE16[(size_t)rr*1024 + c] = (_Float16)(c4[reg] + bb);
            }
        }
    }
}

// ---------------- k_enc: recurrence (0..31) + Xgdec GEMM (32..255) — R8 verbatim ----------------
__global__ void __attribute__((amdgpu_flat_work_group_size(512,512), amdgpu_waves_per_eu(2,2)))
k_enc_rnn(
    const _Float16* __restrict__ Xg16, const _Float16* __restrict__ Whh16,
    const float* __restrict__ h0, const float* __restrict__ c0,
    _Float16* __restrict__ enc_out16,
    const _Float16* __restrict__ emb_in16, const _Float16* __restrict__ dWih16,
    const float* __restrict__ bias_d, _Float16* __restrict__ Xg16dec)
{
    extern __shared__ char smem[];
    const int bx = blockIdx.x, tid = threadIdx.x;
    if (bx >= 32){
        int eng = tid >> 8, ltid = tid & 255;
        _Float16* Bs = (_Float16*)smem + (size_t)eng*(64*264);
        int base = (bx - 32)*2 + eng;      // 0..447
        for (int rnd = 0; rnd < 3; rnd++){
            int tile = rnd*448 + base;
            __syncthreads();
            if (tile < 1024)
                gemm16_body(Bs, ltid, emb_in16, dWih16, bias_d, nullptr, Xg16dec,
                            1024, GF_BIAS|GF_F16OUT, (tile >> 4)*64, (tile & 15)*64);
            else
                __syncthreads();   // match gemm16_body's internal barrier
        }
        return;
    }
    uint4*  wlds = (uint4*)smem;                   // [9][1024]
    uint32* h_u  = (uint32*)(smem + 147456);       // 128 dwords
    float*  g_s  = (float*)(smem + 147968);        // 1024
    const int b = bx;
    const int r0 = tid, r1 = tid + 512;
    const uint4* p0 = (const uint4*)(Whh16 + (size_t)r0*256);
    const uint4* p1 = (const uint4*)(Whh16 + (size_t)r1*256);
    uint4 w0[23], w1[23];
    #pragma unroll
    for (int i = 0; i < 23; i++){ w0[i] = p0[i]; w1[i] = p1[i]; }
    #pragma unroll
    for (int i = 0; i < 9; i++){
        wlds[i*1024 + r0] = p0[23 + i];
        wlds[i*1024 + r1] = p1[23 + i];
    }
    float c = 0.f;
    if (tid < 256){
        c = c0[tid];
        ((_Float16*)h_u)[tid] = (_Float16)h0[tid];
    }
    __syncthreads();
    const uint4* hu4 = (const uint4*)h_u;
    float xg0 = (float)Xg16[(size_t)b*1024 + r0];
    float xg1 = (float)Xg16[(size_t)b*1024 + r1];
    for (int t = 0; t < 128; t++){
        float nxg0 = 0.f, nxg1 = 0.f;
        if (t < 127){
            nxg0 = (float)Xg16[((size_t)((t+1)*32+b))*1024 + r0];
            nxg1 = (float)Xg16[((size_t)((t+1)*32+b))*1024 + r1];
        }
        float a0 = 0.f, a1 = 0.f;
        #pragma unroll
        for (int i = 0; i < 23; i++){
            uint4 hh = hu4[i];
            a0 = dot2f(w0[i].x, hh.x, a0); a0 = dot2f(w0[i].y, hh.y, a0);
            a0 = dot2f(w0[i].z, hh.z, a0); a0 = dot2f(w0[i].w, hh.w, a0);
            a1 = dot2f(w1[i].x, hh.x, a1); a1 = dot2f(w1[i].y, hh.y, a1);
            a1 = dot2f(w1[i].z, hh.z, a1); a1 = dot2f(w1[i].w, hh.w, a1);
        }
        #pragma unroll
        for (int i = 0; i < 9; i++){
            uint4 hh = hu4[23 + i];
            uint4 v0 = wlds[i*1024 + r0];
            uint4 v1 = wlds[i*1024 + r1];
            a0 = dot2f(v0.x, hh.x, a0); a0 = dot2f(v0.y, hh.y, a0);
            a0 = dot2f(v0.z, hh.z, a0); a0 = dot2f(v0.w, hh.w, a0);
            a1 = dot2f(v1.x, hh.x, a1); a1 = dot2f(v1.y, hh.y, a1);
            a1 = dot2f(v1.z, hh.z, a1); a1 = dot2f(v1.w, hh.w, a1);
        }
        g_s[r0] = a0 + xg0;
        g_s[r1] = a1 + xg1;
        __syncthreads();
        if (tid < 256){
            float gi = g_s[tid], gf = g_s[256+tid], gg = g_s[512+tid], go = g_s[768+tid];
            c = sigmf_(gf)*c + sigmf_(gi)*tanhf(gg);
            float hn = sigmf_(go)*tanhf(c);
            enc_out16[((size_t)(t*32+b))*256 + tid] = (_Float16)(0.5f*hn);
            ((_Float16*)h_u)[tid] = (_Float16)hn;
        }
        __syncthreads();
        xg0 = nxg0; xg1 = nxg1;
    }
}

// ---------------- k_decoder: heads + 5 fused decoder steps, block-local ----------------
// 63 blocks x 256 thr, 64 rows each. sos/dech0 computed into LDS; h in LDS;
// c in VGPRs (16 f32x4). gb never materialized (step0 = sos@dWih + h@dWhh).
// Dyn LDS: Bs 33792 + hS 33792 + sS 33792 = 101376 B.
__global__ __launch_bounds__(256) void k_decoder(
    const _Float16* __restrict__ enc_out16,
    const _Float16* __restrict__ sosW16, const float* __restrict__ sos_b,
    const _Float16* __restrict__ dhtW16, const float* __restrict__ dht_b,
    const _Float16* __restrict__ dWih16, const _Float16* __restrict__ dWhh16,
    const float* __restrict__ bias_d, const _Float16* __restrict__ Xgdec16,
    _Float16* __restrict__ dec16)
{
    extern __shared__ char smem[];
    _Float16* Bs = (_Float16*)smem;                 // 64*264
    _Float16* hS = (_Float16*)(smem + 33792);       // 64*264
    _Float16* sS = (_Float16*)(smem + 67584);       // 64*264
    const int tid = threadIdx.x;
    const int wave = tid >> 6, lane = tid & 63;
    const int ln = lane & 15, quad = lane >> 4;
    const int r0 = blockIdx.x * 64;

    // ---- heads: sos -> sS, dech0=tanh(...) -> hS ----
    half8_t aE[8];
    {
        const half8_t* Ap = (const half8_t*)(enc_out16 + (size_t)(r0 + wave*16 + ln)*256 + quad*8);
        #pragma unroll
        for (int ks = 0; ks < 8; ks++) aE[ks] = Ap[ks*4];
    }
    #pragma unroll
    for (int t = 0; t < 8; t++){
        int z = t >> 2;
        int colBlk = (t & 3)*64;
        const _Float16* W = z ? dhtW16 : sosW16;
        __syncthreads();
        #pragma unroll
        for (int i = 0; i < 8; i++){
            int idx = i*256 + tid;
            int row = idx >> 5, c16 = idx & 31;
            *(uint4*)&Bs[row*264 + c16*8] = *(const uint4*)(W + (size_t)(colBlk+row)*256 + c16*8);
        }
        __syncthreads();
        #pragma unroll
        for (int ct = 0; ct < 4; ct++){
            f32x4_t c4 = {0.f,0.f,0.f,0.f};
            const _Float16* bp = &Bs[(ct*16+ln)*264 + quad*8];
            #pragma unroll
            for (int ks = 0; ks < 8; ks++){
                half8_t b = *(const half8_t*)(bp + ks*32);
                c4 = __builtin_amdgcn_mfma_f32_16x16x32_f16(aE[ks], b, c4, 0, 0, 0);
            }
            int c = colBlk + ct*16 + ln;
            float bb = z ? dht_b[c] : sos_b[c];
            #pragma unroll
            for (int reg = 0; reg < 4; reg++){
                int rl = wave*16 + quad*4 + reg;
                float v = c4[reg] + bb;
                if (z) hS[rl*264 + c] = (_Float16)tanhf(v);
                else   sS[rl*264 + c] = (_Float16)v;
            }
        }
    }
    __syncthreads();

    f32x4_t cst[4][4];   // cell state: [ut][strip], positions (r,u) owned by thread

    for (int j = 0; j < 5; j++){
        half8_t aH[8], aS[8];
        {
            const _Float16* hp = &hS[(wave*16+ln)*264 + quad*8];
            #pragma unroll
            for (int ks = 0; ks < 8; ks++) aH[ks] = *(const half8_t*)(hp + ks*32);
        }
        if (j == 0){
            const _Float16* sp = &sS[(wave*16+ln)*264 + quad*8];
            #pragma unroll
            for (int ks = 0; ks < 8; ks++) aS[ks] = *(const half8_t*)(sp + ks*32);
        }
        __syncthreads();   // a-frag reads complete before epilogue rewrites hS
        _Float16* dec_j = dec16 + (size_t)j*4032*256;

        for (int ut = 0; ut < 4; ut++){
            f32x4_t cg[4][4];
            #pragma unroll
            for (int g = 0; g < 4; g++){
                int colBlk = g*256 + ut*64;
                __syncthreads();
                #pragma unroll
                for (int i = 0; i < 8; i++){
                    int idx = i*256 + tid;
                    int row = idx >> 5, c16 = idx & 31;
                    *(uint4*)&Bs[row*264 + c16*8] =
                        *(const uint4*)(dWhh16 + (size_t)(colBlk+row)*256 + c16*8);
                }
                __syncthreads();
                #pragma unroll
                for (int ct = 0; ct < 4; ct++){
                    f32x4_t c4 = {0.f,0.f,0.f,0.f};
                    const _Float16* bp = &Bs[(ct*16+ln)*264 + quad*8];
                    #pragma unroll
                    for (int ks = 0; ks < 8; ks++){
                        half8_t b = *(const half8_t*)(bp + ks*32);
                        c4 = __builtin_amdgcn_mfma_f32_16x16x32_f16(aH[ks], b, c4, 0, 0, 0);
                    }
                    cg[g][ct] = c4;
                }
                if (j == 0){
                    __syncthreads();
                    #pragma unroll
                    for (int i = 0; i < 8; i++){
                        int idx = i*256 + tid;
                        int row = idx >> 5, c16 = idx & 31;
                        *(uint4*)&Bs[row*264 + c16*8] =
                            *(const uint4*)(dWih16 + (size_t)(colBlk+row)*256 + c16*8);
                    }
                    __syncthreads();
                    #pragma unroll
                    for (int ct = 0; ct < 4; ct++){
                        f32x4_t c4 = cg[g][ct];
                        const _Float16* bp = &Bs[(ct*16+ln)*264 + quad*8];
                        #pragma unroll
                        for (int ks = 0; ks < 8; ks++){
                            half8_t b = *(const half8_t*)(bp + ks*32);
                            c4 = __builtin_amdgcn_mfma_f32_16x16x32_f16(aS[ks], b, c4, 0, 0, 0);
                        }
                        cg[g][ct] = c4;
                    }
                }
            }
            // epilogue for this ut
            #pragma unroll
            for (int ct = 0; ct < 4; ct++){
                int u = ut*64 + ct*16 + ln;
                #pragma unroll
                for (int reg = 0; reg < 4; reg++){
                    int rl = wave*16 + quad*4 + reg;
                    int r = r0 + rl;
                    float bi, bf, bg, bo;
                    if (j == 0){
                        bi = bias_d[u]; bf = bias_d[256+u]; bg = bias_d[512+u]; bo = bias_d[768+u];
                    } else {
                        int s = r >> 5, b_ = r & 31;
                        int m = s + j;
                        if (m < 128){
                            const _Float16* bp2 = Xgdec16 + (size_t)(m*32+b_)*1024 + u;
                            bi = (float)bp2[0]; bf = (float)bp2[256]; bg = (float)bp2[512]; bo = (float)bp2[768];
                        } else {
                            bi = bias_d[u]; bf = bias_d[256+u]; bg = bias_d[512+u]; bo = bias_d[768+u];
                        }
                    }
                    float gi = cg[0][ct][reg] + bi;
                    float gf = cg[1][ct][reg] + bf;
                    float gg = cg[2][ct][reg] + bg;
                    float go = cg[3][ct][reg] + bo;
                    float cv = (j == 0) ? 0.0f : cst[ut][ct][reg];
                    cv = sigmf_(gf)*cv + sigmf_(gi)*tanhf(gg);
                    float hv = sigmf_(go)*tanhf(cv);
                    cst[ut][ct][reg] = cv;
                    hS[rl*264 + u] = (_Float16)hv;
                    dec_j[(size_t)r*256 + u] = (_Float16)hv;
                }
            }
        }
        __syncthreads();   // h writes complete before next step's a-frag reads
    }
}

// ---------------- k_logits: 4 vocab quarters + inline tgt/EOS (R8 verbatim) ----------------
__global__ __launch_bounds__(256) void k_logits(
    const _Float16* __restrict__ dec16, const _Float16* __restrict__ emb16,
    const float* __restrict__ biasOff, const int* __restrict__ x,
    float* __restrict__ ps, float* __restrict__ pzt, float* __restrict__ pze)
{
    __shared__ _Float16 Bs[64*264];
    __shared__ int tgt_s[64];
    int tid = threadIdx.x;
    int wave = tid >> 6, lane = tid & 63;
    int ln = lane & 15, quad = lane >> 4;
    int r0 = blockIdx.x * 64;
    int q = blockIdx.y;
    int vt0 = q*16, vt1 = (q == 3) ? 63 : (vt0 + 16);

    if (tid < 64){
        int r = r0 + tid;
        int t = r / 4032, sb = r % 4032;
        int s_ = sb >> 5, b = sb & 31;
        int m = s_ + 1 + t;
        tgt_s[tid] = (m < 128) ? x[b*128 + m] : 0;
    }
    half8_t a[8];
    const half8_t* Ap = (const half8_t*)(dec16 + (size_t)(r0 + wave*16 + ln)*256 + quad*8);
    #pragma unroll
    for (int ks = 0; ks < 8; ks++) a[ks] = Ap[ks*4];
    __syncthreads();
    int tg[4];
    #pragma unroll
    for (int reg = 0; reg < 4; reg++) tg[reg] = tgt_s[wave*16 + quad*4 + reg];

    float s[4]   = {0.f,0.f,0.f,0.f};
    float rzt[4] = {-1e30f,-1e30f,-1e30f,-1e30f};
    float rze[4] = {-1e30f,-1e30f,-1e30f,-1e30f};

    for (int vt = vt0; vt < vt1; vt++){
        int v0 = vt*64;
        __syncthreads();
        #pragma unroll
        for (int i = 0; i < 8; i++){
            int idx = i*256 + tid;
            int row = idx >> 5, c16 = idx & 31;
            *(uint4*)&Bs[row*264 + c16*8] =
                *(const uint4*)(emb16 + (size_t)(v0+row)*256 + c16*8);
        }
        __syncthreads();

        #pragma unroll
        for (int ct = 0; ct < 4; ct++){
            f32x4_t c4 = {0.f,0.f,0.f,0.f};
            const _Float16* bp = &Bs[(ct*16+ln)*264 + quad*8];
            #pragma unroll
            for (int ks = 0; ks < 8; ks++){
                half8_t b = *(const half8_t*)(bp + ks*32);
                c4 = __builtin_amdgcn_mfma_f32_16x16x32_f16(a[ks], b, c4, 0, 0, 0);
            }
            int vv = v0 + ct*16 + ln;
            float bb = biasOff[vv];
            #pragma unroll
            for (int reg = 0; reg < 4; reg++){
                float z = c4[reg] + bb;
                s[reg] += __expf(z);
                if (vv == tg[reg]) rzt[reg] = z;
                if (vv == 3)       rze[reg] = z;
            }
        }
    }
    #pragma unroll
    for (int reg = 0; reg < 4; reg++){
        float vsum = s[reg], vzt = rzt[reg], vze = rze[reg];
        #pragma unroll
        for (int off = 1; off < 16; off <<= 1){
            vsum += __shfl_xor(vsum, off, 64);
            vzt = fmaxf(vzt, __shfl_xor(vzt, off, 64));
            vze = fmaxf(vze, __shfl_xor(vze, off, 64));
        }
        if (ln == 0){
            int r = r0 + wave*16 + quad*4 + reg;
            ps [q*20160 + r] = vsum;
            pzt[q*20160 + r] = vzt;
            pze[q*20160 + r] = vze;
        }
    }
}

// ---------------- k_comb_fin: combine + last-finisher finalize ----------------
__global__ __launch_bounds__(256) void k_comb_fin(
    const float* __restrict__ ps, const float* __restrict__ pzt,
    const float* __restrict__ pze, const int* __restrict__ x,
    const float* __restrict__ is_s, const int* __restrict__ lengths,
    float* __restrict__ tlp, float* __restrict__ eosb,
    float* __restrict__ seg_g, float* __restrict__ out,
    unsigned int* __restrict__ counter)
{
    int tid = threadIdx.x;
    int r = blockIdx.x*256 + tid;
    if (r < 20160){
        float lse = __logf(ps[r] + ps[20160+r] + ps[2*20160+r] + ps[3*20160+r]);
        int t = r / 4032, sb = r % 4032;
        int s_ = sb >> 5, b = sb & 31;
        int m = s_ + 1 + t;
        int tg = (m < 128) ? x[b*128 + m] : 0;
        float zt = pzt[(tg >> 10)*20160 + r];   // quarters are 1024-col aligned
        float ze = pze[r];                       // EOS=3 -> quarter 0
        if (t < 4)  tlp[(t*126+s_)*32 + b]      = zt - lse;
        if (t >= 1) eosb[((t-1)*126+s_)*32 + b] = ze - lse;
    }
    __threadfence();
    __syncthreads();
    __shared__ int lastBlk;
    if (tid == 0){
        unsigned old = __hip_atomic_fetch_add(counter, 1u, __ATOMIC_ACQ_REL,
                                              __HIP_MEMORY_SCOPE_AGENT);
        lastBlk = (old == 78) ? 1 : 0;
    }
    __syncthreads();
    if (!lastBlk) return;
    __threadfence();

    int k = tid >> 5, b = tid & 31;
    if (tid < 128){
        for (int s = 0; s < 126; s++){
            float cum = 0.f;
            for (int kk = 0; kk <= k; kk++) cum += tlp[(kk*126+s)*32 + b];
            if (k >= 1){
                for (int kk = 1; kk <= k; kk++){
                    int m = s+1+kk;
                    if (m < 128) cum += is_s[m*32+b];
                }
                cum += is_s[(s+1)*32 + b];
            }
            float lp = cum + eosb[(k*126+s)*32 + b];
            int jl = min(4, 126 - s);
            if (k >= jl) lp = LOGNEG;
            seg_g[(s*4+k)*32 + b] = lp;
        }
    }
    __threadfence_block();
    __syncthreads();
    __shared__ float nll_s[32];
    if (tid < 32){
        int target = lengths[tid] - 2;
        float b0 = 0.f, b1 = LOGNEG, b2 = LOGNEG, b3 = LOGNEG;
        float nllb = 0.f;
        for (int e = 1; e <= 126; e++){
            float v0 = b0 + seg_g[((e-1)*4+0)*32 + tid];
            float v1 = b1 + ((e >= 2) ? seg_g[((e-2)*4+1)*32 + tid] : LOGNEG);
            float v2 = b2 + ((e >= 3) ? seg_g[((e-3)*4+2)*32 + tid] : LOGNEG);
            float v3 = b3 + ((e >= 4) ? seg_g[((e-4)*4+3)*32 + tid] : LOGNEG);
            float mx = fmaxf(fmaxf(v0,v1), fmaxf(v2,v3));
            float a = mx + logf(expf(v0-mx)+expf(v1-mx)+expf(v2-mx)+expf(v3-mx));
            if (e == target) nllb = -a;
            b3 = b2; b2 = b1; b1 = b0; b0 = a;
        }
        nll_s[tid] = nllb;
    }
    __syncthreads();
    if (tid == 0){
        float tot = 0.f; int lsum = 0;
        for (int i = 0; i < 32; i++){ tot += nll_s[i]; lsum += lengths[i]; }
        out[0] = tot / (float)(lsum - 64);
    }
}

extern "C" void kernel_launch(void* const* d_in, const int* in_sizes, int n_in,
                              void* d_out, int out_size, void* d_ws, size_t ws_size,
                              hipStream_t stream)
{
    const int*   x        = (const int*)  d_in[0];
    const int*   lengths  = (const int*)  d_in[1];
    const float* emb      = (const float*)d_in[2];
    const float* e2v_b    = (const float*)d_in[3];
    const float* enc_Wih  = (const float*)d_in[4];
    const float* enc_Whh  = (const float*)d_in[5];
    const float* enc_bih  = (const float*)d_in[6];
    const float* enc_bhh  = (const float*)d_in[7];
    const float* enc_h0   = (const float*)d_in[8];
    const float* enc_c0   = (const float*)d_in[9];
    const float* dec_Wih  = (const float*)d_in[10];
    const float* dec_Whh  = (const float*)d_in[11];
    const float* dec_bih  = (const float*)d_in[12];
    const float* dec_bhh  = (const float*)d_in[13];
    const float* dht_W    = (const float*)d_in[14];
    const float* dht_b    = (const float*)d_in[15];
    const float* sos_W    = (const float*)d_in[16];
    const float* sos_b    = (const float*)d_in[17];
    float* out = (float*)d_out;

    char* wsb = (char*)d_ws;
    size_t off = 0;
    auto alloc = [&](size_t bytes)->void*{
        void* p = (void*)(wsb + off);
        off += ((bytes + 255)/256)*256;
        return p;
    };
    _Float16* emb16    = (_Float16*)alloc((size_t)4032*256*2);
    _Float16* dWih16   = (_Float16*)alloc((size_t)1024*256*2);
    _Float16* dWhh16   = (_Float16*)alloc((size_t)1024*256*2);
    _Float16* eWhh16   = (_Float16*)alloc((size_t)1024*256*2);
    _Float16* sosW16   = (_Float16*)alloc((size_t)256*256*2);
    _Float16* dhtW16   = (_Float16*)alloc((size_t)256*256*2);
    _Float16* emb_in16 = (_Float16*)alloc((size_t)4096*256*2);
    _Float16* XgE16    = (_Float16*)alloc((size_t)4096*1024*2);
    _Float16* Xgdec16  = (_Float16*)alloc((size_t)4096*1024*2);
    _Float16* enc_out16= (_Float16*)alloc((size_t)4096*256*2);
    _Float16* dec16    = (_Float16*)alloc((size_t)5*4032*256*2);
    float*    biasOff  = (float*)alloc(4032*4);
    float*    bias_d   = (float*)alloc(1024*4);
    float*    is_s     = (float*)alloc(4096*4);
    float*    ps       = (float*)alloc((size_t)4*20160*4);
    float*    pzt      = (float*)alloc((size_t)4*20160*4);
    float*    pze      = (float*)alloc((size_t)4*20160*4);
    float*    tlp      = (float*)alloc((size_t)4*126*32*4);
    float*    eosb     = (float*)alloc((size_t)4*126*32*4);
    float*    seg_g    = (float*)alloc((size_t)126*4*32*4);
    unsigned int* counter = (unsigned int*)alloc(256);
    (void)ws_size; (void)in_sizes; (void)n_in; (void)out_size;

    hipFuncSetAttribute(reinterpret_cast<const void*>(k_enc_rnn),
                        hipFuncAttributeMaxDynamicSharedMemorySize, 152064);
    hipFuncSetAttribute(reinterpret_cast<const void*>(k_decoder),
                        hipFuncAttributeMaxDynamicSharedMemorySize, 101376);

    // 0. zero the last-finisher counter (ws is poisoned 0xAA every call)
    hipMemsetAsync(counter, 0, sizeof(unsigned int), stream);
    // 1. prep: packs + gather + XgE GEMM (from raw f32)
    k_prep<<<12740, 256, 0, stream>>>(x, emb, e2v_b, enc_Wih, dec_Wih, dec_Whh, enc_Whh,
        sos_W, dht_W, enc_bih, enc_bhh, dec_bih, dec_bhh,
        emb16, biasOff, dWih16, dWhh16, eWhh16, sosW16, dhtW16, bias_d,
        emb_in16, is_s, XgE16);
    // 2. encoder recurrence + fused Xgdec GEMM
    k_enc_rnn<<<256, 512, 152064, stream>>>(XgE16, eWhh16, enc_h0, enc_c0, enc_out16,
        emb_in16, dWih16, bias_d, Xgdec16);
    // 3. decoder: heads + 5 steps, block-local
    k_decoder<<<63, 256, 101376, stream>>>(enc_out16, sosW16, sos_b, dhtW16, dht_b,
        dWih16, dWhh16, bias_d, Xgdec16, dec16);
    // 4. logits: 4 vocab quarters + inline tgt/EOS
    k_logits<<<dim3(315,4), 256, 0, stream>>>(dec16, emb16, biasOff, x, ps, pzt, pze);
    // 5. combine + last-finisher finalize
    k_comb_fin<<<79, 256, 0, stream>>>(ps, pzt, pze, x, is_s, lengths,
        tlp, eosb, seg_g, out, counter);
}

// Round 11
// 827.426 us; speedup vs baseline: 2.8701x; 1.2475x over previous
//
#include <hip/hip_runtime.h>
#include <math.h>

// SegmentalLM forward. V=4000 E=H=256 M=128 B=32 L=4, S=126, NROW=5*4032=20160.
//
// R9 FAILED: grid.sync ~125us on 8 non-coherent XCD L2s. R10 FAILED: 63-block
// decoder fusion serialized the stage chain (330us vs 127us as 252-blk chain).
// R11: decoder back to 252-block per-step dispatches; step-0 fuses sos@dWih
//      (no gb dispatch / 8MB roundtrip); logits 128 rows/block (2x MAC per
//      staged byte); prep/enc/comb_fin from R10 (verified).

#define LOGNEG -1000000.0f
#define GF_BIAS 1
#define GF_TANH 2
#define GF_F16OUT 16
#define ZSHIFT 8.0f

typedef unsigned int uint32;
typedef _Float16 half2_t __attribute__((ext_vector_type(2)));
typedef _Float16 half8_t __attribute__((ext_vector_type(8)));
typedef float    f32x4_t __attribute__((ext_vector_type(4)));

__device__ __forceinline__ float sigmf_(float x){ return 1.0f/(1.0f+expf(-x)); }

__device__ __forceinline__ float dot2f(uint32 w, uint32 h, float acc){
#if __has_builtin(__builtin_amdgcn_fdot2)
    return __builtin_amdgcn_fdot2(__builtin_bit_cast(half2_t, w),
                                  __builtin_bit_cast(half2_t, h), acc, false);
#else
    half2_t a = __builtin_bit_cast(half2_t, w);
    half2_t b = __builtin_bit_cast(half2_t, h);
    return acc + (float)a[0]*(float)b[0] + (float)a[1]*(float)b[1];
#endif
}

// ---- 64x64 f16 MFMA tile body (256-thr engine; threads >=256 idle) ----
__device__ __forceinline__ void gemm16_body(
    _Float16* Bs, int tid,
    const _Float16* __restrict__ A, const _Float16* __restrict__ W,
    const float* __restrict__ bias, float* __restrict__ C,
    _Float16* __restrict__ C16, int N, int flags, int rowBlk, int colBlk)
{
    int wave = tid >> 6, lane = tid & 63;
    int ln = lane & 15, quad = lane >> 4;
    half8_t a[8];
    if (tid < 256){
        #pragma unroll
        for (int i = 0; i < 8; i++){
            int idx = i*256 + tid;
            int row = idx >> 5, c16 = idx & 31;
            *(uint4*)&Bs[row*264 + c16*8] =
                *(const uint4*)(W + (size_t)(colBlk+row)*256 + c16*8);
        }
        const half8_t* Ap = (const half8_t*)(A + (size_t)(rowBlk + wave*16 + ln)*256 + quad*8);
        #pragma unroll
        for (int ks = 0; ks < 8; ks++) a[ks] = Ap[ks*4];
    }
    __syncthreads();
    if (tid < 256){
        #pragma unroll
        for (int ct = 0; ct < 4; ct++){
            f32x4_t c4 = {0.f,0.f,0.f,0.f};
            const _Float16* bp = &Bs[(ct*16+ln)*264 + quad*8];
            #pragma unroll
            for (int ks = 0; ks < 8; ks++){
                half8_t b = *(const half8_t*)(bp + ks*32);
                c4 = __builtin_amdgcn_mfma_f32_16x16x32_f16(a[ks], b, c4, 0, 0, 0);
            }
            int c = colBlk + ct*16 + ln;
            #pragma unroll
            for (int reg = 0; reg < 4; reg++){
                int r = rowBlk + wave*16 + quad*4 + reg;
                float v = c4[reg];
                if (flags & GF_BIAS) v += bias[c];
                if (flags & GF_TANH) v = tanhf(v);
                if (flags & GF_F16OUT) C16[(size_t)r*N + c] = (_Float16)v;
                else                   C  [(size_t)r*N + c] = v;
            }
        }
    }
}

// ---------------- k_prep: packs + gather + XgE GEMM from raw f32 (R10 verbatim) ----------------
__global__ __launch_bounds__(256) void k_prep(
    const int* __restrict__ x,
    const float* __restrict__ emb, const float* __restrict__ e2v_b,
    const float* __restrict__ eWih, const float* __restrict__ dWih,
    const float* __restrict__ dWhh, const float* __restrict__ eWhh,
    const float* __restrict__ sosW, const float* __restrict__ dhtW,
    const float* __restrict__ ebih, const float* __restrict__ ebhh,
    const float* __restrict__ dbih, const float* __restrict__ dbhh,
    _Float16* __restrict__ emb16, float* __restrict__ biasOff,
    _Float16* __restrict__ dWih16, _Float16* __restrict__ dWhh16,
    _Float16* __restrict__ eWhh16, _Float16* __restrict__ sosW16,
    _Float16* __restrict__ dhtW16, float* __restrict__ bias_d,
    _Float16* __restrict__ emb_in16, float* __restrict__ is_s,
    _Float16* __restrict__ XgE16)
{
    __shared__ _Float16 Bs[64*264];
    int bx = blockIdx.x, tid = threadIdx.x;
    if (bx < 4032){
        int row = bx;
        emb16[(size_t)row*256 + tid] = (row < 4000) ? (_Float16)emb[(size_t)row*256 + tid] : (_Float16)0.0f;
        if (tid == 0) biasOff[row] = (row < 4000) ? (e2v_b[row] - ZSHIFT) : -200.0f;
    } else if (bx < 5056){
        int r = bx - 4032; dWih16[(size_t)r*256 + tid] = (_Float16)dWih[(size_t)r*256 + tid];
    } else if (bx < 6080){
        int r = bx - 5056; dWhh16[(size_t)r*256 + tid] = (_Float16)dWhh[(size_t)r*256 + tid];
    } else if (bx < 7104){
        int r = bx - 6080; eWhh16[(size_t)r*256 + tid] = (_Float16)eWhh[(size_t)r*256 + tid];
    } else if (bx < 7360){
        int r = bx - 7104; sosW16[(size_t)r*256 + tid] = (_Float16)sosW[(size_t)r*256 + tid];
    } else if (bx < 7616){
        int r = bx - 7360; dhtW16[(size_t)r*256 + tid] = (_Float16)dhtW[(size_t)r*256 + tid];
    } else if (bx < 7620){
        int j = (bx - 7616)*256 + tid;
        if (j < 1024) bias_d[j] = dbih[j] + dbhh[j];
    } else if (bx < 11716){
        int ri = bx - 7620;               // < 4096
        int m = ri >> 5, b = ri & 31;
        int tok = x[b*128 + m];
        emb_in16[(size_t)ri*256 + tid] = (_Float16)emb[(size_t)tok*256 + tid];
        if (tid == 0) is_s[ri] = (tok <= 2) ? LOGNEG : 0.0f;
    } else {
        int tile = bx - 11716;            // < 1024
        int rowBlk = (tile >> 4)*64, colBlk = (tile & 15)*64;
        #pragma unroll
        for (int i = 0; i < 8; i++){
            int idx = i*256 + tid;
            int row = idx >> 5, c16 = idx & 31;
            const float* src = eWih + (size_t)(colBlk+row)*256 + c16*8;
            float4 f0 = *(const float4*)src;
            float4 f1 = *(const float4*)(src + 4);
            half8_t hv;
            hv[0]=(_Float16)f0.x; hv[1]=(_Float16)f0.y; hv[2]=(_Float16)f0.z; hv[3]=(_Float16)f0.w;
            hv[4]=(_Float16)f1.x; hv[5]=(_Float16)f1.y; hv[6]=(_Float16)f1.z; hv[7]=(_Float16)f1.w;
            *(half8_t*)&Bs[row*264 + c16*8] = hv;
        }
        int wave = tid >> 6, lane = tid & 63;
        int ln = lane & 15, quad = lane >> 4;
        int r = rowBlk + wave*16 + ln;
        int m = r >> 5, b_ = r & 31;
        int tok = x[b_*128 + m];
        half8_t a[8];
        #pragma unroll
        for (int ks = 0; ks < 8; ks++){
            const float* ap = emb + (size_t)tok*256 + quad*8 + ks*32;
            float4 f0 = *(const float4*)ap;
            float4 f1 = *(const float4*)(ap + 4);
            half8_t hv;
            hv[0]=(_Float16)f0.x; hv[1]=(_Float16)f0.y; hv[2]=(_Float16)f0.z; hv[3]=(_Float16)f0.w;
            hv[4]=(_Float16)f1.x; hv[5]=(_Float16)f1.y; hv[6]=(_Float16)f1.z; hv[7]=(_Float16)f1.w;
            a[ks] = hv;
        }
        __syncthreads();
        #pragma unroll
        for (int ct = 0; ct < 4; ct++){
            f32x4_t c4 = {0.f,0.f,0.f,0.f};
            const _Float16* bp = &Bs[(ct*16+ln)*264 + quad*8];
            #pragma unroll
            for (int ks = 0; ks < 8; ks++){
                half8_t b = *(const half8_t*)(bp + ks*32);
                c4 = __builtin_amdgcn_mfma_f32_16x16x32_f16(a[ks], b, c4, 0, 0, 0);
            }
            int c = colBlk + ct*16 + ln;
            float bb = ebih[c] + ebhh[c];
            #pragma unroll
            for (int reg = 0; reg < 4; reg++){
                int rr = rowBlk + wave*16 + quad*4 + reg;
                XgE16[(size_t)rr*1024 + c] = (_Float16)(c4[reg] + bb);
            }
        }
    }
}

// ---------------- k_enc: recurrence (0..31) + Xgdec GEMM (32..255) (R10 verbatim) ----------------
__global__ void __attribute__((amdgpu_flat_work_group_size(512,512), amdgpu_waves_per_eu(2,2)))
k_enc_rnn(
    const _Float16* __restrict__ Xg16, const _Float16* __restrict__ Whh16,
    const float* __restrict__ h0, const float* __restrict__ c0,
    _Float16* __restrict__ enc_out16,
    const _Float16* __restrict__ emb_in16, const _Float16* __restrict__ dWih16,
    const float* __restrict__ bias_d, _Float16* __restrict__ Xg16dec)
{
    extern __shared__ char smem[];
    const int bx = blockIdx.x, tid = threadIdx.x;
    if (bx >= 32){
        int eng = tid >> 8, ltid = tid & 255;
        _Float16* Bs = (_Float16*)smem + (size_t)eng*(64*264);
        int base = (bx - 32)*2 + eng;      // 0..447
        for (int rnd = 0; rnd < 3; rnd++){
            int tile = rnd*448 + base;
            __syncthreads();
            if (tile < 1024)
                gemm16_body(Bs, ltid, emb_in16, dWih16, bias_d, nullptr, Xg16dec,
                            1024, GF_BIAS|GF_F16OUT, (tile >> 4)*64, (tile & 15)*64);
            else
                __syncthreads();
        }
        return;
    }
    uint4*  wlds = (uint4*)smem;                   // [9][1024]
    uint32* h_u  = (uint32*)(smem + 147456);       // 128 dwords
    float*  g_s  = (float*)(smem + 147968);        // 1024
    const int b = bx;
    const int r0 = tid, r1 = tid + 512;
    const uint4* p0 = (const uint4*)(Whh16 + (size_t)r0*256);
    const uint4* p1 = (const uint4*)(Whh16 + (size_t)r1*256);
    uint4 w0[23], w1[23];
    #pragma unroll
    for (int i = 0; i < 23; i++){ w0[i] = p0[i]; w1[i] = p1[i]; }
    #pragma unroll
    for (int i = 0; i < 9; i++){
        wlds[i*1024 + r0] = p0[23 + i];
        wlds[i*1024 + r1] = p1[23 + i];
    }
    float c = 0.f;
    if (tid < 256){
        c = c0[tid];
        ((_Float16*)h_u)[tid] = (_Float16)h0[tid];
    }
    __syncthreads();
    const uint4* hu4 = (const uint4*)h_u;
    float xg0 = (float)Xg16[(size_t)b*1024 + r0];
    float xg1 = (float)Xg16[(size_t)b*1024 + r1];
    for (int t = 0; t < 128; t++){
        float nxg0 = 0.f, nxg1 = 0.f;
        if (t < 127){
            nxg0 = (float)Xg16[((size_t)((t+1)*32+b))*1024 + r0];
            nxg1 = (float)Xg16[((size_t)((t+1)*32+b))*1024 + r1];
        }
        float a0 = 0.f, a1 = 0.f;
        #pragma unroll
        for (int i = 0; i < 23; i++){
            uint4 hh = hu4[i];
            a0 = dot2f(w0[i].x, hh.x, a0); a0 = dot2f(w0[i].y, hh.y, a0);
            a0 = dot2f(w0[i].z, hh.z, a0); a0 = dot2f(w0[i].w, hh.w, a0);
            a1 = dot2f(w1[i].x, hh.x, a1); a1 = dot2f(w1[i].y, hh.y, a1);
            a1 = dot2f(w1[i].z, hh.z, a1); a1 = dot2f(w1[i].w, hh.w, a1);
        }
        #pragma unroll
        for (int i = 0; i < 9; i++){
            uint4 hh = hu4[23 + i];
            uint4 v0 = wlds[i*1024 + r0];
            uint4 v1 = wlds[i*1024 + r1];
            a0 = dot2f(v0.x, hh.x, a0); a0 = dot2f(v0.y, hh.y, a0);
            a0 = dot2f(v0.z, hh.z, a0); a0 = dot2f(v0.w, hh.w, a0);
            a1 = dot2f(v1.x, hh.x, a1); a1 = dot2f(v1.y, hh.y, a1);
            a1 = dot2f(v1.w, hh.w, a1); a1 = dot2f(v1.z, hh.z, a1);
        }
        g_s[r0] = a0 + xg0;
        g_s[r1] = a1 + xg1;
        __syncthreads();
        if (tid < 256){
            float gi = g_s[tid], gf = g_s[256+tid], gg = g_s[512+tid], go = g_s[768+tid];
            c = sigmf_(gf)*c + sigmf_(gi)*tanhf(gg);
            float hn = sigmf_(go)*tanhf(c);
            enc_out16[((size_t)(t*32+b))*256 + tid] = (_Float16)(0.5f*hn);
            ((_Float16*)h_u)[tid] = (_Float16)hn;
        }
        __syncthreads();
        xg0 = nxg0; xg1 = nxg1;
    }
}

// ---------------- k_head: sos (z=0) + dech0 (z=1) ----------------
__global__ __launch_bounds__(256) void k_head(
    const _Float16* __restrict__ enc_out16,
    const _Float16* __restrict__ sosW16, const float* __restrict__ sos_b, _Float16* __restrict__ sos16,
    const _Float16* __restrict__ dhtW16, const float* __restrict__ dht_b, _Float16* __restrict__ dech0_16)
{
    __shared__ _Float16 Bs[64*264];
    int z = blockIdx.z;
    gemm16_body(Bs, threadIdx.x, enc_out16,
                z ? dhtW16 : sosW16, z ? dht_b : sos_b, nullptr,
                z ? dech0_16 : sos16, 256,
                z ? (GF_BIAS|GF_TANH|GF_F16OUT) : (GF_BIAS|GF_F16OUT),
                blockIdx.y*64, blockIdx.x*64);
}

// ---------------- k_dec_step: one decoder step, 252 blocks ----------------
// j==0: gates = sos@dWih^T + dech0@dWhh^T + bias_d (double MFMA; no gb buffer).
// j>=1: gates = h@dWhh^T + Xgdec[m] (or bias_d for m>=128).
__global__ __launch_bounds__(256) void k_dec_step(
    const _Float16* __restrict__ hprev, const _Float16* __restrict__ sosA,
    const _Float16* __restrict__ dWhh16, const _Float16* __restrict__ dWih16,
    const _Float16* __restrict__ base16, const float* __restrict__ bias_d,
    float* __restrict__ dec_c, _Float16* __restrict__ dec16_j, int jstep)
{
    __shared__ _Float16 Bs[64*264];
    int tid = threadIdx.x;
    int wave = tid >> 6, lane = tid & 63;
    int ln = lane & 15, quad = lane >> 4;
    int u0 = blockIdx.x * 64, r0 = blockIdx.y * 64;

    half8_t aH[8], aS[8];
    {
        const half8_t* Ap = (const half8_t*)(hprev + (size_t)(r0 + wave*16 + ln)*256 + quad*8);
        #pragma unroll
        for (int ks = 0; ks < 8; ks++) aH[ks] = Ap[ks*4];
    }
    if (jstep == 0){
        const half8_t* Ap = (const half8_t*)(sosA + (size_t)(r0 + wave*16 + ln)*256 + quad*8);
        #pragma unroll
        for (int ks = 0; ks < 8; ks++) aS[ks] = Ap[ks*4];
    }

    f32x4_t cg[4][4];
    #pragma unroll
    for (int g = 0; g < 4; g++){
        int colBlk = g*256 + u0;
        __syncthreads();
        #pragma unroll
        for (int i = 0; i < 8; i++){
            int idx = i*256 + tid;
            int row = idx >> 5, c16 = idx & 31;
            *(uint4*)&Bs[row*264 + c16*8] =
                *(const uint4*)(dWhh16 + (size_t)(colBlk+row)*256 + c16*8);
        }
        __syncthreads();
        #pragma unroll
        for (int ct = 0; ct < 4; ct++){
            f32x4_t c4 = {0.f,0.f,0.f,0.f};
            const _Float16* bp = &Bs[(ct*16+ln)*264 + quad*8];
            #pragma unroll
            for (int ks = 0; ks < 8; ks++){
                half8_t b = *(const half8_t*)(bp + ks*32);
                c4 = __builtin_amdgcn_mfma_f32_16x16x32_f16(aH[ks], b, c4, 0, 0, 0);
            }
            cg[g][ct] = c4;
        }
        if (jstep == 0){
            __syncthreads();
            #pragma unroll
            for (int i = 0; i < 8; i++){
                int idx = i*256 + tid;
                int row = idx >> 5, c16 = idx & 31;
                *(uint4*)&Bs[row*264 + c16*8] =
                    *(const uint4*)(dWih16 + (size_t)(colBlk+row)*256 + c16*8);
            }
            __syncthreads();
            #pragma unroll
            for (int ct = 0; ct < 4; ct++){
                f32x4_t c4 = cg[g][ct];
                const _Float16* bp = &Bs[(ct*16+ln)*264 + quad*8];
                #pragma unroll
                for (int ks = 0; ks < 8; ks++){
                    half8_t b = *(const half8_t*)(bp + ks*32);
                    c4 = __builtin_amdgcn_mfma_f32_16x16x32_f16(aS[ks], b, c4, 0, 0, 0);
                }
                cg[g][ct] = c4;
            }
        }
    }
    #pragma unroll
    for (int ct = 0; ct < 4; ct++){
        int u = u0 + ct*16 + ln;
        #pragma unroll
        for (int reg = 0; reg < 4; reg++){
            int r = r0 + wave*16 + quad*4 + reg;
            float bi, bf, bg, bo;
            if (jstep == 0){
                bi = bias_d[u]; bf = bias_d[256+u]; bg = bias_d[512+u]; bo = bias_d[768+u];
            } else {
                int s = r >> 5, b_ = r & 31;
                int m = s + jstep;
                if (m < 128){
                    const _Float16* bp2 = base16 + (size_t)(m*32+b_)*1024 + u;
                    bi = (float)bp2[0]; bf = (float)bp2[256]; bg = (float)bp2[512]; bo = (float)bp2[768];
                } else {
                    bi = bias_d[u]; bf = bias_d[256+u]; bg = bias_d[512+u]; bo = bias_d[768+u];
                }
            }
            float gi = cg[0][ct][reg] + bi;
            float gf = cg[1][ct][reg] + bf;
            float gg = cg[2][ct][reg] + bg;
            float go = cg[3][ct][reg] + bo;
            float cv = (jstep == 0) ? 0.0f : dec_c[(size_t)r*256 + u];
            cv = sigmf_(gf)*cv + sigmf_(gi)*tanhf(gg);
            float hv = sigmf_(go)*tanhf(cv);
            dec_c[(size_t)r*256 + u] = cv;
            dec16_j[(size_t)r*256 + u] = (_Float16)hv;
        }
    }
}

// ---------------- k_logits: 128 rows/block, 4 vocab quarters, inline tgt/EOS ----------------
// grid (158, 4). Two A-frag sets per wave -> each staged 32KB emb tile used 2x.
__global__ __launch_bounds__(256) void k_logits(
    const _Float16* __restrict__ dec16, const _Float16* __restrict__ emb16,
    const float* __restrict__ biasOff, const int* __restrict__ x,
    float* __restrict__ ps, float* __restrict__ pzt, float* __restrict__ pze)
{
    __shared__ _Float16 Bs[64*264];
    __shared__ int tgt_s[128];
    int tid = threadIdx.x;
    int wave = tid >> 6, lane = tid & 63;
    int ln = lane & 15, quad = lane >> 4;
    int r0 = blockIdx.x * 128;
    int q = blockIdx.y;
    int vt0 = q*16, vt1 = (q == 3) ? 63 : (vt0 + 16);

    if (tid < 128){
        int r = r0 + tid;
        if (r >= 20160) r = 20159;
        int t = r / 4032, sb = r % 4032;
        int s_ = sb >> 5, b = sb & 31;
        int m = s_ + 1 + t;
        tgt_s[tid] = (m < 128) ? x[b*128 + m] : 0;
    }
    half8_t aA[8], aB[8];
    {
        int ra = r0 + wave*16 + ln;        if (ra >= 20160) ra = 20159;
        int rb = r0 + 64 + wave*16 + ln;   if (rb >= 20160) rb = 20159;
        const half8_t* Ap = (const half8_t*)(dec16 + (size_t)ra*256 + quad*8);
        const half8_t* Bp = (const half8_t*)(dec16 + (size_t)rb*256 + quad*8);
        #pragma unroll
        for (int ks = 0; ks < 8; ks++){ aA[ks] = Ap[ks*4]; aB[ks] = Bp[ks*4]; }
    }
    __syncthreads();
    int tgA[4], tgB[4];
    #pragma unroll
    for (int reg = 0; reg < 4; reg++){
        tgA[reg] = tgt_s[wave*16 + quad*4 + reg];
        tgB[reg] = tgt_s[64 + wave*16 + quad*4 + reg];
    }

    float sA[4] = {0.f,0.f,0.f,0.f}, sB[4] = {0.f,0.f,0.f,0.f};
    float ztA[4] = {-1e30f,-1e30f,-1e30f,-1e30f}, ztB[4] = {-1e30f,-1e30f,-1e30f,-1e30f};
    float zeA[4] = {-1e30f,-1e30f,-1e30f,-1e30f}, zeB[4] = {-1e30f,-1e30f,-1e30f,-1e30f};

    for (int vt = vt0; vt < vt1; vt++){
        int v0 = vt*64;
        __syncthreads();
        #pragma unroll
        for (int i = 0; i < 8; i++){
            int idx = i*256 + tid;
            int row = idx >> 5, c16 = idx & 31;
            *(uint4*)&Bs[row*264 + c16*8] =
                *(const uint4*)(emb16 + (size_t)(v0+row)*256 + c16*8);
        }
        __syncthreads();

        #pragma unroll
        for (int ct = 0; ct < 4; ct++){
            f32x4_t cA = {0.f,0.f,0.f,0.f}, cB = {0.f,0.f,0.f,0.f};
            const _Float16* bp = &Bs[(ct*16+ln)*264 + quad*8];
            #pragma unroll
            for (int ks = 0; ks < 8; ks++){
                half8_t b = *(const half8_t*)(bp + ks*32);
                cA = __builtin_amdgcn_mfma_f32_16x16x32_f16(aA[ks], b, cA, 0, 0, 0);
                cB = __builtin_amdgcn_mfma_f32_16x16x32_f16(aB[ks], b, cB, 0, 0, 0);
            }
            int vv = v0 + ct*16 + ln;
            float bb = biasOff[vv];
            #pragma unroll
            for (int reg = 0; reg < 4; reg++){
                float zA = cA[reg] + bb, zB = cB[reg] + bb;
                sA[reg] += __expf(zA);
                sB[reg] += __expf(zB);
                if (vv == tgA[reg]) ztA[reg] = zA;
                if (vv == tgB[reg]) ztB[reg] = zB;
                if (vv == 3){ zeA[reg] = zA; zeB[reg] = zB; }
            }
        }
    }
    #pragma unroll
    for (int reg = 0; reg < 4; reg++){
        float vsA = sA[reg], vtA = ztA[reg], veA = zeA[reg];
        float vsB = sB[reg], vtB = ztB[reg], veB = zeB[reg];
        #pragma unroll
        for (int off = 1; off < 16; off <<= 1){
            vsA += __shfl_xor(vsA, off, 64);
            vsB += __shfl_xor(vsB, off, 64);
            vtA = fmaxf(vtA, __shfl_xor(vtA, off, 64));
            vtB = fmaxf(vtB, __shfl_xor(vtB, off, 64));
            veA = fmaxf(veA, __shfl_xor(veA, off, 64));
            veB = fmaxf(veB, __shfl_xor(veB, off, 64));
        }
        if (ln == 0){
            int rA = r0 + wave*16 + quad*4 + reg;
            int rB = rA + 64;
            if (rA < 20160){ ps[q*20160+rA] = vsA; pzt[q*20160+rA] = vtA; pze[q*20160+rA] = veA; }
            if (rB < 20160){ ps[q*20160+rB] = vsB; pzt[q*20160+rB] = vtB; pze[q*20160+rB] = veB; }
        }
    }
}

// ---------------- k_comb_fin: combine + last-finisher finalize (R10 verbatim) ----------------
__global__ __launch_bounds__(256) void k_comb_fin(
    const float* __restrict__ ps, const float* __restrict__ pzt,
    const float* __restrict__ pze, const int* __restrict__ x,
    const float* __restrict__ is_s, const int* __restrict__ lengths,
    float* __restrict__ tlp, float* __restrict__ eosb,
    float* __restrict__ seg_g, float* __restrict__ out,
    unsigned int* __restrict__ counter)
{
    int tid = threadIdx.x;
    int r = blockIdx.x*256 + tid;
    if (r < 20160){
        float lse = __logf(ps[r] + ps[20160+r] + ps[2*20160+r] + ps[3*20160+r]);
        int t = r / 4032, sb = r % 4032;
        int s_ = sb >> 5, b = sb & 31;
        int m = s_ + 1 + t;
        int tg = (m < 128) ? x[b*128 + m] : 0;
        float zt = pzt[(tg >> 10)*20160 + r];
        float ze = pze[r];
        if (t < 4)  tlp[(t*126+s_)*32 + b]      = zt - lse;
        if (t >= 1) eosb[((t-1)*126+s_)*32 + b] = ze - lse;
    }
    __threadfence();
    __syncthreads();
    __shared__ int lastBlk;
    if (tid == 0){
        unsigned old = __hip_atomic_fetch_add(counter, 1u, __ATOMIC_ACQ_REL,
                                              __HIP_MEMORY_SCOPE_AGENT);
        lastBlk = (old == 78) ? 1 : 0;
    }
    __syncthreads();
    if (!lastBlk) return;
    __threadfence();

    int k = tid >> 5, b = tid & 31;
    if (tid < 128){
        for (int s = 0; s < 126; s++){
            float cum = 0.f;
            for (int kk = 0; kk <= k; kk++) cum += tlp[(kk*126+s)*32 + b];
            if (k >= 1){
                for (int kk = 1; kk <= k; kk++){
                    int m = s+1+kk;
                    if (m < 128) cum += is_s[m*32+b];
                }
                cum += is_s[(s+1)*32 + b];
            }
            float lp = cum + eosb[(k*126+s)*32 + b];
            int jl = min(4, 126 - s);
            if (k >= jl) lp = LOGNEG;
            seg_g[(s*4+k)*32 + b] = lp;
        }
    }
    __threadfence_block();
    __syncthreads();
    __shared__ float nll_s[32];
    if (tid < 32){
        int target = lengths[tid] - 2;
        float b0 = 0.f, b1 = LOGNEG, b2 = LOGNEG, b3 = LOGNEG;
        float nllb = 0.f;
        for (int e = 1; e <= 126; e++){
            float v0 = b0 + seg_g[((e-1)*4+0)*32 + tid];
            float v1 = b1 + ((e >= 2) ? seg_g[((e-2)*4+1)*32 + tid] : LOGNEG);
            float v2 = b2 + ((e >= 3) ? seg_g[((e-3)*4+2)*32 + tid] : LOGNEG);
            float v3 = b3 + ((e >= 4) ? seg_g[((e-4)*4+3)*32 + tid] : LOGNEG);
            float mx = fmaxf(fmaxf(v0,v1), fmaxf(v2,v3));
            float a = mx + logf(expf(v0-mx)+expf(v1-mx)+expf(v2-mx)+expf(v3-mx));
            if (e == target) nllb = -a;
            b3 = b2; b2 = b1; b1 = b0; b0 = a;
        }
        nll_s[tid] = nllb;
    }
    __syncthreads();
    if (tid == 0){
        float tot = 0.f; int lsum = 0;
        for (int i = 0; i < 32; i++){ tot += nll_s[i]; lsum += lengths[i]; }
        out[0] = tot / (float)(lsum - 64);
    }
}

extern "C" void kernel_launch(void* const* d_in, const int* in_sizes, int n_in,
                              void* d_out, int out_size, void* d_ws, size_t ws_size,
                              hipStream_t stream)
{
    const int*   x        = (const int*)  d_in[0];
    const int*   lengths  = (const int*)  d_in[1];
    const float* emb      = (const float*)d_in[2];
    const float* e2v_b    = (const float*)d_in[3];
    const float* enc_Wih  = (const float*)d_in[4];
    const float* enc_Whh  = (const float*)d_in[5];
    const float* enc_bih  = (const float*)d_in[6];
    const float* enc_bhh  = (const float*)d_in[7];
    const float* enc_h0   = (const float*)d_in[8];
    const float* enc_c0   = (const float*)d_in[9];
    const float* dec_Wih  = (const float*)d_in[10];
    const float* dec_Whh  = (const float*)d_in[11];
    const float* dec_bih  = (const float*)d_in[12];
    const float* dec_bhh  = (const float*)d_in[13];
    const float* dht_W    = (const float*)d_in[14];
    const float* dht_b    = (const float*)d_in[15];
    const float* sos_W    = (const float*)d_in[16];
    const float* sos_b    = (const float*)d_in[17];
    float* out = (float*)d_out;

    char* wsb = (char*)d_ws;
    size_t off = 0;
    auto alloc = [&](size_t bytes)->void*{
        void* p = (void*)(wsb + off);
        off += ((bytes + 255)/256)*256;
        return p;
    };
    _Float16* emb16    = (_Float16*)alloc((size_t)4032*256*2);
    _Float16* dWih16   = (_Float16*)alloc((size_t)1024*256*2);
    _Float16* dWhh16   = (_Float16*)alloc((size_t)1024*256*2);
    _Float16* eWhh16   = (_Float16*)alloc((size_t)1024*256*2);
    _Float16* sosW16   = (_Float16*)alloc((size_t)256*256*2);
    _Float16* dhtW16   = (_Float16*)alloc((size_t)256*256*2);
    _Float16* emb_in16 = (_Float16*)alloc((size_t)4096*256*2);
    _Float16* XgE16    = (_Float16*)alloc((size_t)4096*1024*2);
    _Float16* Xgdec16  = (_Float16*)alloc((size_t)4096*1024*2);
    _Float16* enc_out16= (_Float16*)alloc((size_t)4096*256*2);
    _Float16* sos16    = (_Float16*)alloc((size_t)4032*256*2);
    _Float16* dech0_16 = (_Float16*)alloc((size_t)4032*256*2);
    _Float16* dec16    = (_Float16*)alloc((size_t)5*4032*256*2);
    float*    dec_c    = (float*)alloc((size_t)4032*256*4);
    float*    biasOff  = (float*)alloc(4032*4);
    float*    bias_d   = (float*)alloc(1024*4);
    float*    is_s     = (float*)alloc(4096*4);
    float*    ps       = (float*)alloc((size_t)4*20160*4);
    float*    pzt      = (float*)alloc((size_t)4*20160*4);
    float*    pze      = (float*)alloc((size_t)4*20160*4);
    float*    tlp      = (float*)alloc((size_t)4*126*32*4);
    float*    eosb     = (float*)alloc((size_t)4*126*32*4);
    float*    seg_g    = (float*)alloc((size_t)126*4*32*4);
    unsigned int* counter = (unsigned int*)alloc(256);
    (void)ws_size; (void)in_sizes; (void)n_in; (void)out_size;

    hipFuncSetAttribute(reinterpret_cast<const void*>(k_enc_rnn),
                        hipFuncAttributeMaxDynamicSharedMemorySize, 152064);

    // 0. zero the last-finisher counter
    hipMemsetAsync(counter, 0, sizeof(unsigned int), stream);
    // 1. prep: packs + gather + XgE GEMM
    k_prep<<<12740, 256, 0, stream>>>(x, emb, e2v_b, enc_Wih, dec_Wih, dec_Whh, enc_Whh,
        sos_W, dht_W, enc_bih, enc_bhh, dec_bih, dec_bhh,
        emb16, biasOff, dWih16, dWhh16, eWhh16, sosW16, dhtW16, bias_d,
        emb_in16, is_s, XgE16);
    // 2. encoder recurrence + fused Xgdec GEMM
    k_enc_rnn<<<256, 512, 152064, stream>>>(XgE16, eWhh16, enc_h0, enc_c0, enc_out16,
        emb_in16, dWih16, bias_d, Xgdec16);
    // 3. heads
    k_head<<<dim3(4,63,2), 256, 0, stream>>>(enc_out16, sosW16, sos_b, sos16,
        dhtW16, dht_b, dech0_16);
    // 4. decoder: 5 per-step dispatches (252 blocks each; j=0 fuses sos@dWih)
    for (int j = 0; j < 5; j++){
        const _Float16* hA = (j == 0) ? dech0_16 : (dec16 + (size_t)(j-1)*4032*256);
        k_dec_step<<<dim3(4,63), 256, 0, stream>>>(hA, sos16, dWhh16, dWih16,
            Xgdec16, bias_d, dec_c, dec16 + (size_t)j*4032*256, j);
    }
    // 5. logits: 128 rows/block x 4 quarters
    k_logits<<<dim3(158,4), 256, 0, stream>>>(dec16, emb16, biasOff, x, ps, pzt, pze);
    // 6. combine + last-finisher finalize
    k_comb_fin<<<79, 256, 0, stream>>>(ps, pzt, pze, x, is_s, lengths,
        tlp, eosb, seg_g, out, counter);
}